// Round 4
// baseline (122.135 us; speedup 1.0000x reference)
//
#include <hip/hip_runtime.h>

// DisjointDense: out[b] = x[b] @ W[sel[b]] + Bw[sel[b]]
// B=4096, D_IN=256, D_OUT=256, N_DISJOINT=64, all fp32.
//
// R4:
//  - XCD-affinity: blockIdx = quad*64 + d, so all 16 blocks of bucket d are
//    congruent mod 8 -> same XCD -> W[d] L2-filled once (FETCH 79->~30MB).
//  - x operands: vector broadcast loads (vmcnt, in-order) ping-pong prefetched,
//    replacing scalar s_loads whose out-of-order lgkmcnt forced full drains.
//  - bucketize: ballot per row (coalesced 256B loads) + LDS histogram.

#define NBLK 64
#define BCAP 1024
#define CPAD 16   // one counter per 64B cache line

__global__ __launch_bounds__(256) void dd_bucketize(
    const float* __restrict__ onehot,   // [4096, 64]
    int* __restrict__ counts,           // [64*CPAD], zeroed
    int* __restrict__ buckets)          // [64, BCAP]
{
    __shared__ int rowd[256];
    __shared__ int lhist[NBLK];
    __shared__ int lbase[NBLK];
    const int t = threadIdx.x;
    const int w = t >> 6;
    const int lane = t & 63;
    if (t < NBLK) lhist[t] = 0;

    const int row0 = blockIdx.x * 256 + w * 64;
#pragma unroll 8
    for (int i = 0; i < 64; ++i) {
        const float v = onehot[(size_t)(row0 + i) * NBLK + lane];  // coalesced 256B
        const unsigned long long m = __ballot(v > 0.5f);
        const int d = (int)__ffsll(m) - 1;
        if (lane == 0) rowd[w * 64 + i] = d;
    }
    __syncthreads();

    const int d = rowd[t];
    const int slot = atomicAdd(&lhist[d], 1);      // LDS atomic
    __syncthreads();
    if (t < NBLK) lbase[t] = atomicAdd(&counts[t * CPAD], lhist[t]);
    __syncthreads();
    buckets[d * BCAP + lbase[d] + slot] = blockIdx.x * 256 + t;
}

__global__ __launch_bounds__(256, 4) void dd_compute(
    const float* __restrict__ x,        // [4096, 256]
    const float* __restrict__ W,        // [64, 256, 256]  (d, k, col)
    const float* __restrict__ Bw,       // [64, 256]
    const int* __restrict__ counts,     // [64*CPAD]
    const int* __restrict__ buckets,    // [64, BCAP]
    float* __restrict__ out)            // [4096, 256]
{
    const int t    = threadIdx.x;
    const int lane = t & 63;
    const int ct   = t >> 6;                   // wave = col-group
    const int d    = blockIdx.x & 63;          // same-d blocks == d (mod 8) -> one XCD
    const int quad = blockIdx.x >> 6;          // 0..15
    const int c    = ct * 64 + lane;

    const int cnt = counts[d * CPAD];
    const float* Wd  = W + ((size_t)d << 16) + c;   // W[d][k][c], k-stride 256
    const float bias = Bw[d * 256 + c];

    for (int base = quad * 4; base < cnt; base += 64) {
        int  rid[4];
        bool valid[4];
        const float* xr[4];
#pragma unroll
        for (int j = 0; j < 4; ++j) {
            const int idx = base + j;
            valid[j] = (idx < cnt);
            int r = buckets[d * BCAP + (valid[j] ? idx : cnt - 1)];
            r = __builtin_amdgcn_readfirstlane(r);
            rid[j] = r;
            xr[j]  = x + ((size_t)r << 8);
        }

        float acc[4];
#pragma unroll
        for (int j = 0; j < 4; ++j) acc[j] = bias;

        float  wa[8], wb[8];
        float4 xa[4][2], xb[4][2];
#pragma unroll
        for (int i = 0; i < 8; ++i) wa[i] = Wd[i * 256];
#pragma unroll
        for (int j = 0; j < 4; ++j) {
            xa[j][0] = *(const float4*)(xr[j] + 0);   // broadcast vector load (vmcnt)
            xa[j][1] = *(const float4*)(xr[j] + 4);
        }

#pragma unroll 1
        for (int k0 = 0; k0 < 256; k0 += 16) {
            // prefetch half B (k0+8) while computing half A (k0)
#pragma unroll
            for (int i = 0; i < 8; ++i) wb[i] = Wd[((k0 + 8 + i) & 255) * 256];
#pragma unroll
            for (int j = 0; j < 4; ++j) {
                xb[j][0] = *(const float4*)(xr[j] + ((k0 + 8)  & 255));
                xb[j][1] = *(const float4*)(xr[j] + ((k0 + 12) & 255));
            }
#pragma unroll
            for (int j = 0; j < 4; ++j) {
                acc[j] = fmaf(xa[j][0].x, wa[0], acc[j]);
                acc[j] = fmaf(xa[j][0].y, wa[1], acc[j]);
                acc[j] = fmaf(xa[j][0].z, wa[2], acc[j]);
                acc[j] = fmaf(xa[j][0].w, wa[3], acc[j]);
                acc[j] = fmaf(xa[j][1].x, wa[4], acc[j]);
                acc[j] = fmaf(xa[j][1].y, wa[5], acc[j]);
                acc[j] = fmaf(xa[j][1].z, wa[6], acc[j]);
                acc[j] = fmaf(xa[j][1].w, wa[7], acc[j]);
            }
            // prefetch half A' (k0+16) while computing half B (k0+8)
#pragma unroll
            for (int i = 0; i < 8; ++i) wa[i] = Wd[((k0 + 16 + i) & 255) * 256];
#pragma unroll
            for (int j = 0; j < 4; ++j) {
                xa[j][0] = *(const float4*)(xr[j] + ((k0 + 16) & 255));
                xa[j][1] = *(const float4*)(xr[j] + ((k0 + 20) & 255));
            }
#pragma unroll
            for (int j = 0; j < 4; ++j) {
                acc[j] = fmaf(xb[j][0].x, wb[0], acc[j]);
                acc[j] = fmaf(xb[j][0].y, wb[1], acc[j]);
                acc[j] = fmaf(xb[j][0].z, wb[2], acc[j]);
                acc[j] = fmaf(xb[j][0].w, wb[3], acc[j]);
                acc[j] = fmaf(xb[j][1].x, wb[4], acc[j]);
                acc[j] = fmaf(xb[j][1].y, wb[5], acc[j]);
                acc[j] = fmaf(xb[j][1].z, wb[6], acc[j]);
                acc[j] = fmaf(xb[j][1].w, wb[7], acc[j]);
            }
        }

#pragma unroll
        for (int j = 0; j < 4; ++j) {
            if (valid[j]) out[((size_t)rid[j] << 8) + c] = acc[j];
        }
    }
}

extern "C" void kernel_launch(void* const* d_in, const int* in_sizes, int n_in,
                              void* d_out, int out_size, void* d_ws, size_t ws_size,
                              hipStream_t stream) {
    const float* x      = (const float*)d_in[0];   // [4096, 256]
    const float* onehot = (const float*)d_in[1];   // [4096, 64]
    const float* W      = (const float*)d_in[2];   // [64, 256, 256]
    const float* Bw     = (const float*)d_in[3];   // [64, 256]
    float* out = (float*)d_out;                    // [4096, 256]

    int* counts  = (int*)d_ws;                             // 64*CPAD ints (4 KB)
    int* buckets = (int*)((char*)d_ws + NBLK * CPAD * 4);  // 64*BCAP ints (256 KB)

    hipMemsetAsync(counts, 0, NBLK * CPAD * sizeof(int), stream);
    dd_bucketize<<<16, 256, 0, stream>>>(onehot, counts, buckets);
    dd_compute<<<NBLK * 16, 256, 0, stream>>>(x, W, Bw, counts, buckets, out);
}